// Round 1
// baseline (314.669 us; speedup 1.0000x reference)
//
#include <hip/hip_runtime.h>

#define DI static __device__ __forceinline__

typedef short s16x8 __attribute__((ext_vector_type(8)));
typedef float f32x4 __attribute__((ext_vector_type(4)));

DI unsigned short f2b(float f) {
  union { float f; unsigned u; } v; v.f = f;
  unsigned r = (v.u + 0x7FFF + ((v.u >> 16) & 1)) >> 16;  // RNE
  return (unsigned short)r;
}
DI float b2f(unsigned short s) {
  union { unsigned u; float f; } v; v.u = ((unsigned)s) << 16;
  return v.f;
}
DI f32x4 MFMA(s16x8 a, s16x8 b, f32x4 c) {
  return __builtin_amdgcn_mfma_f32_16x16x32_bf16(a, b, c, 0, 0, 0);
}

// ---------------- hypernet h-stack: x[M,10] -> h[M,64] (Lin+ReLU, 2x residual)
// x_lds: [MT][32] bf16 (zero-padded K), winT: [64n][32k], wresT: [2][64n][64k]
// h_lds out: [MT][64] bf16. hval keeps each lane's D-positions for residual add.
template<int NMF>
DI void run_stack(const unsigned short* x_lds, const unsigned short* winT,
                  const unsigned short* wresT,
                  const float* bin, const float* bres,
                  unsigned short* h_lds, float (&hval)[3][4][4])
{
  const int t = threadIdx.x;
  const int l = t & 63, wv = t >> 6;
  const int lrow = l & 15, lk8 = (l >> 4) * 8, lr4 = (l >> 4) * 4;

  // ---- GEMM1: K=32 (one k-step)
  s16x8 bw[4];
#pragma unroll
  for (int nt = 0; nt < 4; nt++)
    bw[nt] = *(const s16x8*)&winT[(nt*16 + lrow)*32 + lk8];
#pragma unroll
  for (int i = 0; i < 3; i++) {
    int mf = wv + i*4;
    if (mf < NMF) {
      s16x8 a = *(const s16x8*)&x_lds[(mf*16 + lrow)*32 + lk8];
#pragma unroll
      for (int nt = 0; nt < 4; nt++) {
        f32x4 d = MFMA(a, bw[nt], f32x4{0.f,0.f,0.f,0.f});
        float bb = bin[nt*16 + lrow];
#pragma unroll
        for (int r = 0; r < 4; r++)
          hval[i][nt][r] = fmaxf(d[r] + bb, 0.f);
      }
#pragma unroll
      for (int nt = 0; nt < 4; nt++)
#pragma unroll
        for (int r = 0; r < 4; r++)
          h_lds[(mf*16 + lr4 + r)*64 + nt*16 + lrow] = f2b(hval[i][nt][r]);
    }
  }
  __syncthreads();

  // ---- 2 residual layers, K=64 (2 k-steps)
#pragma unroll
  for (int d = 0; d < 2; d++) {
    const unsigned short* wt = wresT + d*64*64;
    s16x8 bwr[4][2];
#pragma unroll
    for (int nt = 0; nt < 4; nt++)
#pragma unroll
      for (int s = 0; s < 2; s++)
        bwr[nt][s] = *(const s16x8*)&wt[(nt*16 + lrow)*64 + s*32 + lk8];
    s16x8 af[3][2];
#pragma unroll
    for (int i = 0; i < 3; i++) {
      int mf = wv + i*4;
      if (mf < NMF) {
#pragma unroll
        for (int s = 0; s < 2; s++)
          af[i][s] = *(const s16x8*)&h_lds[(mf*16 + lrow)*64 + s*32 + lk8];
      }
    }
    __syncthreads();   // all reads of h done before overwriting
#pragma unroll
    for (int i = 0; i < 3; i++) {
      int mf = wv + i*4;
      if (mf < NMF) {
#pragma unroll
        for (int nt = 0; nt < 4; nt++) {
          f32x4 acc = {0.f,0.f,0.f,0.f};
          acc = MFMA(af[i][0], bwr[nt][0], acc);
          acc = MFMA(af[i][1], bwr[nt][1], acc);
          float bb = bres[d*64 + nt*16 + lrow];
#pragma unroll
          for (int r = 0; r < 4; r++)
            hval[i][nt][r] = fmaxf(acc[r] + bb, 0.f) + hval[i][nt][r];
        }
#pragma unroll
        for (int nt = 0; nt < 4; nt++)
#pragma unroll
          for (int r = 0; r < 4; r++)
            h_lds[(mf*16 + lr4 + r)*64 + nt*16 + lrow] = f2b(hval[i][nt][r]);
      }
    }
    __syncthreads();   // h ready for next layer / epilogue
  }
}

template<int MT>
DI void stage_x(const float* __restrict__ fr, unsigned short* x_lds) {
  for (int idx = threadIdx.x; idx < MT*32; idx += 256) {
    int row = idx >> 5, c = idx & 31;
    float v = (c < 10) ? fr[row*10 + c] : 0.f;
    x_lds[idx] = f2b(v);
  }
}
DI void stage_w(const float* __restrict__ win, const float* __restrict__ wres,
                unsigned short* winT, unsigned short* wresT) {
  for (int idx = threadIdx.x; idx < 64*32; idx += 256) {
    int n = idx >> 5, k = idx & 31;
    winT[idx] = (k < 10) ? f2b(win[k*64 + n]) : (unsigned short)0;
  }
  for (int idx = threadIdx.x; idx < 2*64*64; idx += 256) {
    int d = idx >> 12, rem = idx & 4095, n = rem >> 6, k = rem & 63;
    wresT[idx] = f2b(wres[d*4096 + k*64 + n]);
  }
}

// MODE 0: hypernet + P-build (P[n][k*10+f] = sum_e h[k]*x[f]; sx at 640..649; pad to 672)
// MODE 1: attack head: hob stack -> qB, how stack -> q_attack
template<int ITEMS, int MODE>
__global__ __launch_bounds__(256) void khyp(
    const float* __restrict__ feats,
    const float* __restrict__ win,  const float* __restrict__ bin,
    const float* __restrict__ wres, const float* __restrict__ bres,
    unsigned short* __restrict__ Pout,
    const float* __restrict__ win2,  const float* __restrict__ bin2,
    const float* __restrict__ wres2, const float* __restrict__ bres2,
    const float* __restrict__ whobw, const float* __restrict__ hob_b,
    const float* __restrict__ g, const float* __restrict__ hb,
    float* __restrict__ qout)
{
  constexpr int MT = ITEMS * 16;
  __shared__ unsigned short x_lds[MT*32];
  __shared__ unsigned short winT[64*32];
  __shared__ unsigned short wresT[2*64*64];
  __shared__ unsigned short h_lds[MT*64];
  __shared__ float qB[MT];

  const int t = threadIdx.x;
  const long rowbase = (long)blockIdx.x * MT;
  float hval[3][4][4];

  stage_x<MT>(feats + rowbase*10, x_lds);

  if (MODE == 0) {
    stage_w(win, wres, winT, wresT);
    __syncthreads();
    run_stack<ITEMS>(x_lds, winT, wresT, bin, bres, h_lds, hval);

    // P-build epilogue: 16 agents x 64 k, 4 (a,k) pairs per thread
#pragma unroll
    for (int rep = 0; rep < 4; rep++) {
      int idx = t + rep*256;
      int a = idx >> 6, k = idx & 63;
      float acc[10];
#pragma unroll
      for (int f = 0; f < 10; f++) acc[f] = 0.f;
      for (int e = 0; e < ITEMS; e++) {
        int row = a*ITEMS + e;
        float hv = b2f(h_lds[row*64 + k]);
#pragma unroll
        for (int f = 0; f < 10; f++)
          acc[f] += hv * b2f(x_lds[row*32 + f]);
      }
      unsigned short* Pp = Pout + ((long)blockIdx.x*16 + a)*672 + k*10;
#pragma unroll
      for (int f = 0; f < 10; f++) Pp[f] = f2b(acc[f]);
    }
    if (t < 160) {  // sx[n][f] = sum_e x[f]  (for bout term)
      int a = t/10, f = t - (t/10)*10;
      float s = 0.f;
      for (int e = 0; e < ITEMS; e++) s += b2f(x_lds[(a*ITEMS + e)*32 + f]);
      Pout[((long)blockIdx.x*16 + a)*672 + 640 + f] = f2b(s);
    }
    if (t < 352) {  // zero-pad K 650..671
      int a = t/22, c = t - (t/22)*22;
      Pout[((long)blockIdx.x*16 + a)*672 + 650 + c] = 0;
    }
  } else {
    // ---- stack B: hob -> qB[row] = h_hob . hob_wout[:,0]
    stage_w(win2, wres2, winT, wresT);
    __syncthreads();
    run_stack<ITEMS>(x_lds, winT, wresT, bin2, bres2, h_lds, hval);
    if (t < MT) {
      float s = 0.f;
      for (int k = 0; k < 64; k++) s += b2f(h_lds[t*64 + k]) * whobw[k];
      qB[t] = s;
    }
    __syncthreads();
    // ---- stack A: how -> q_attack = h_how . g[n] + qB + hb[n] + hob_bout
    stage_w(win, wres, winT, wresT);
    __syncthreads();
    run_stack<ITEMS>(x_lds, winT, wresT, bin, bres, h_lds, hval);
    if (t < MT) {
      int n = blockIdx.x*16 + t/ITEMS;
      int e = t - (t/ITEMS)*ITEMS;
      const float* gp = g + (long)n*64;
      float s = qB[t] + hb[n] + hob_b[0];
      for (int k = 0; k < 64; k++) s += b2f(h_lds[t*64 + k]) * gp[k];
      qout[n*17 + 6 + e] = s;
    }
  }
}

// ---------------- emb GEMM: [10240, 672(bf16 P)] @ BT -> emb[10240,64] f32
__global__ __launch_bounds__(256) void kpgemm(
    const unsigned short* __restrict__ P,
    const float* __restrict__ wout, const float* __restrict__ bout,
    float* __restrict__ emb)
{
  __shared__ unsigned short A_lds[128*32];
  __shared__ unsigned short BT_lds[64*32];
  const int t = threadIdx.x;
  const int l = t & 63, wv = t >> 6;
  const int lrow = l & 15, lk8 = (l >> 4)*8, lr4 = (l >> 4)*4;
  const int m0 = blockIdx.x * 128;

  f32x4 acc[2][4];
#pragma unroll
  for (int i = 0; i < 2; i++)
#pragma unroll
    for (int nt = 0; nt < 4; nt++) acc[i][nt] = f32x4{0.f,0.f,0.f,0.f};

  for (int kk = 0; kk < 672; kk += 32) {
#pragma unroll
    for (int i2 = 0; i2 < 2; i2++) {
      int aidx = t + i2*256;
      int row = aidx >> 2, c8 = (aidx & 3) * 8;
      *(s16x8*)&A_lds[row*32 + c8] = *(const s16x8*)&P[(long)(m0+row)*672 + kk + c8];
    }
#pragma unroll
    for (int i2 = 0; i2 < 8; i2++) {
      int idx = t + i2*256;
      int kfl = idx >> 6, j = idx & 63;
      int kfg = kk + kfl;
      float v;
      if (kfg < 640)      { int k = kfg/10, f = kfg - k*10; v = wout[k*640 + f*64 + j]; }
      else if (kfg < 650) { v = bout[(kfg-640)*64 + j]; }
      else                { v = 0.f; }
      BT_lds[j*32 + kfl] = f2b(v);
    }
    __syncthreads();
    s16x8 bf[4];
#pragma unroll
    for (int nt = 0; nt < 4; nt++)
      bf[nt] = *(const s16x8*)&BT_lds[(nt*16 + lrow)*32 + lk8];
#pragma unroll
    for (int i = 0; i < 2; i++) {
      int mf = wv*2 + i;
      s16x8 af = *(const s16x8*)&A_lds[(mf*16 + lrow)*32 + lk8];
#pragma unroll
      for (int nt = 0; nt < 4; nt++) acc[i][nt] = MFMA(af, bf[nt], acc[i][nt]);
    }
    __syncthreads();
  }
#pragma unroll
  for (int i = 0; i < 2; i++)
#pragma unroll
    for (int nt = 0; nt < 4; nt++)
#pragma unroll
      for (int r = 0; r < 4; r++) {
        int row = m0 + (wv*2 + i)*16 + lr4 + r;
        emb[(long)row*64 + nt*16 + lrow] = acc[i][nt][r];
      }
}

// ---------------- fc1 + embeddings + GRU + fc2 + g + hb ; 16 agents/block
__global__ __launch_bounds__(1024) void kgru(
    const float* __restrict__ own, const float* __restrict__ fc1_w, const float* __restrict__ fc1_b,
    const float* __restrict__ agent_emb, const float* __restrict__ action_emb,
    const int* __restrict__ agent_idx, const int* __restrict__ last_action_idx,
    const float* __restrict__ emb_en, const float* __restrict__ emb_al,
    const float* __restrict__ hidden,
    const float* __restrict__ wi, const float* __restrict__ wh,
    const float* __restrict__ bi, const float* __restrict__ bh,
    const float* __restrict__ fc2_w, const float* __restrict__ fc2_b,
    const float* __restrict__ how_wout, const float* __restrict__ how_bout,
    float* __restrict__ qout, float* __restrict__ hhout,
    float* __restrict__ g, float* __restrict__ hbuf)
{
  __shared__ unsigned short wils[64*192];
  __shared__ unsigned short whls[64*192];
  __shared__ float xs[1024], hs[1024], hhs[1024];
  const int t = threadIdx.x;
#pragma unroll
  for (int i = 0; i < 12; i++) {
    int idx = t + i*1024;
    wils[idx] = f2b(wi[idx]);
    whls[idx] = f2b(wh[idx]);
  }
  const int a = t >> 6, j = t & 63;
  const int n = blockIdx.x*16 + a;

  float v = fc1_b[j];
  const float* ow = own + (long)n*32;
#pragma unroll
  for (int f = 0; f < 32; f++) v += ow[f] * fc1_w[f*64 + j];
  int ai = agent_idx[n], la = last_action_idx[n];
  v += agent_emb[ai*64 + j] + action_emb[la*64 + j]
     + emb_en[(long)n*64 + j] + emb_al[(long)n*64 + j];
  float x = fmaxf(v, 0.f);
  float h = hidden[(long)n*64 + j];
  xs[t] = x; hs[t] = h;
  __syncthreads();

  float gir = bi[j], giz = bi[64+j], gin = bi[128+j];
  float ghr = bh[j], ghz = bh[64+j], ghn = bh[128+j];
  const int ab = a*64;
#pragma unroll 8
  for (int k = 0; k < 64; k++) {
    float xk = xs[ab+k], hk = hs[ab+k];
    gir += xk * b2f(wils[k*192 + j]);
    giz += xk * b2f(wils[k*192 + 64 + j]);
    gin += xk * b2f(wils[k*192 + 128 + j]);
    ghr += hk * b2f(whls[k*192 + j]);
    ghz += hk * b2f(whls[k*192 + 64 + j]);
    ghn += hk * b2f(whls[k*192 + 128 + j]);
  }
  float r  = 1.f/(1.f + __expf(-(gir + ghr)));
  float z  = 1.f/(1.f + __expf(-(giz + ghz)));
  float nn = tanhf(gin + r*ghn);
  float hh = (1.f - z)*nn + z*h;
  hhout[(long)n*64 + j] = hh;
  hhs[t] = hh;
  __syncthreads();

  if (j < 6) {                       // q_normal
    float q = fc2_b[j];
    for (int k = 0; k < 64; k++) q += hhs[ab+k] * fc2_w[k*6 + j];
    qout[n*17 + j] = q;
  }
  {                                  // g[n][k] = sum_j hh[j] * how_wout[k][j]  (k = this j)
    const float* wr = how_wout + j*64;
    float gv = 0.f;
    for (int k = 0; k < 64; k++) gv += hhs[ab+k] * wr[k];
    g[(long)n*64 + j] = gv;
  }
  if (j == 0) {                      // hb[n] = hh . how_bout
    float s = 0.f;
    for (int k = 0; k < 64; k++) s += hhs[ab+k] * how_bout[k];
    hbuf[n] = s;
  }
}

extern "C" void kernel_launch(void* const* d_in, const int* in_sizes, int n_in,
                              void* d_out, int out_size, void* d_ws, size_t ws_size,
                              hipStream_t stream)
{
  const float* own        = (const float*)d_in[0];
  const float* enemy      = (const float*)d_in[1];
  const float* ally       = (const float*)d_in[2];
  const float* hidden     = (const float*)d_in[3];
  const float* fc1_w      = (const float*)d_in[4];
  const float* fc1_b      = (const float*)d_in[5];
  const float* agent_emb  = (const float*)d_in[6];
  const float* action_emb = (const float*)d_in[7];
  const float* hen_win  = (const float*)d_in[8];  const float* hen_bin  = (const float*)d_in[9];
  const float* hen_wres = (const float*)d_in[10]; const float* hen_bres = (const float*)d_in[11];
  const float* hen_wout = (const float*)d_in[12]; const float* hen_bout = (const float*)d_in[13];
  const float* hal_win  = (const float*)d_in[14]; const float* hal_bin  = (const float*)d_in[15];
  const float* hal_wres = (const float*)d_in[16]; const float* hal_bres = (const float*)d_in[17];
  const float* hal_wout = (const float*)d_in[18]; const float* hal_bout = (const float*)d_in[19];
  const float* gru_wi = (const float*)d_in[20];   const float* gru_wh = (const float*)d_in[21];
  const float* gru_bi = (const float*)d_in[22];   const float* gru_bh = (const float*)d_in[23];
  const float* fc2_w  = (const float*)d_in[24];   const float* fc2_b  = (const float*)d_in[25];
  const float* how_win  = (const float*)d_in[26]; const float* how_bin  = (const float*)d_in[27];
  const float* how_wres = (const float*)d_in[28]; const float* how_bres = (const float*)d_in[29];
  const float* how_wout = (const float*)d_in[30]; const float* how_bout = (const float*)d_in[31];
  const float* hob_win  = (const float*)d_in[32]; const float* hob_bin  = (const float*)d_in[33];
  const float* hob_wres = (const float*)d_in[34]; const float* hob_bres = (const float*)d_in[35];
  const float* hob_wout = (const float*)d_in[36]; const float* hob_bout = (const float*)d_in[37];
  const int* agent_idx   = (const int*)d_in[38];
  const int* last_action = (const int*)d_in[39];

  char* w = (char*)d_ws;
  unsigned short* P = (unsigned short*)w;                         // 10240*672*2 = 13,762,560 B
  float* emb_en = (float*)(w + 13762560);                         // 2,621,440 B
  float* emb_al = (float*)(w + 13762560 + 2621440);               // 2,621,440 B
  float* g      = (float*)(w + 13762560 + 2*2621440);             // 2,621,440 B
  float* hb     = (float*)(w + 13762560 + 3*2621440);             //    40,960 B

  float* q  = (float*)d_out;
  float* hh = q + 1024*10*17;

  khyp<11,0><<<640,256,0,stream>>>(enemy, hen_win, hen_bin, hen_wres, hen_bres, P,
      nullptr,nullptr,nullptr,nullptr,nullptr,nullptr,nullptr,nullptr,nullptr);
  kpgemm<<<80,256,0,stream>>>(P, hen_wout, hen_bout, emb_en);
  khyp<9,0><<<640,256,0,stream>>>(ally, hal_win, hal_bin, hal_wres, hal_bres, P,
      nullptr,nullptr,nullptr,nullptr,nullptr,nullptr,nullptr,nullptr,nullptr);
  kpgemm<<<80,256,0,stream>>>(P, hal_wout, hal_bout, emb_al);
  kgru<<<640,1024,0,stream>>>(own, fc1_w, fc1_b, agent_emb, action_emb, agent_idx, last_action,
      emb_en, emb_al, hidden, gru_wi, gru_wh, gru_bi, gru_bh, fc2_w, fc2_b,
      how_wout, how_bout, q, hh, g, hb);
  khyp<11,1><<<640,256,0,stream>>>(enemy, how_win, how_bin, how_wres, how_bres, nullptr,
      hob_win, hob_bin, hob_wres, hob_bres, hob_wout, hob_bout, g, hb, q);
}

// Round 2
// 80.509 us; speedup vs baseline: 3.9085x; 3.9085x over previous
//
#include <hip/hip_runtime.h>

#define DI static __device__ __forceinline__

typedef short s16x8 __attribute__((ext_vector_type(8)));
typedef short s16x4 __attribute__((ext_vector_type(4)));
typedef float f32x4 __attribute__((ext_vector_type(4)));

DI unsigned short f2b(float f) {
  union { float f; unsigned u; } v; v.f = f;
  return (unsigned short)((v.u + 0x7FFF + ((v.u >> 16) & 1)) >> 16);  // RNE
}
DI float b2f(unsigned short s) {
  union { unsigned u; float f; } v; v.u = ((unsigned)s) << 16;
  return v.f;
}
DI f32x4 MFMA(s16x8 a, s16x8 b, f32x4 c) {
  return __builtin_amdgcn_mfma_f32_16x16x32_bf16(a, b, c, 0, 0, 0);
}
DI s16x8 ldg8(const unsigned short* p) { return *(const s16x8*)p; }

// ---- ws layout (short offsets) ----
#define OFF_WEN   0        // [2048 winT | 8192 wresT] per stack
#define OFF_WAL   10240
#define OFF_WHOW  20480
#define OFF_WHOB  30720
#define OFF_BGEN  40960    // [21][64][32]
#define OFF_BGAL  83968
#define OFF_WIT   126976   // [192][64]
#define OFF_WHT   139264
#define OFF_FC1T  151552   // [64][32]
#define OFF_FC2E  153600   // [16][64] cols:0-5 fc2, 6 how_bout
#define OFF_HOWT  154624   // [64][64]
#define OFF_HOBT  158720   // [16][64] row0 = hob_wout
#define SH_END    159744
// byte offsets (f32 / bf16 buffers)
#define B_EMB_EN  (SH_END*2)
#define B_EMB_AL  (B_EMB_EN + 2621440)
#define B_HB      (B_EMB_AL + 2621440)
#define B_GBF     (B_HB + 40960)

#define HSTR 72   // h/x/hh LDS row stride in shorts (16B-aligned, ~2-way banks)
#define PSTR 680  // P row stride in shorts (16B-aligned, ~2-way banks)

// ================= kprep: convert all weights to bf16 MFMA-friendly layouts
__global__ __launch_bounds__(256) void kprep(
    const float* __restrict__ hen_win, const float* __restrict__ hen_wres,
    const float* __restrict__ hal_win, const float* __restrict__ hal_wres,
    const float* __restrict__ how_win, const float* __restrict__ how_wres,
    const float* __restrict__ hob_win, const float* __restrict__ hob_wres,
    const float* __restrict__ hen_wout, const float* __restrict__ hen_bout,
    const float* __restrict__ hal_wout, const float* __restrict__ hal_bout,
    const float* __restrict__ gru_wi, const float* __restrict__ gru_wh,
    const float* __restrict__ fc1_w, const float* __restrict__ fc2_w,
    const float* __restrict__ how_bout, const float* __restrict__ how_wout,
    const float* __restrict__ hob_wout,
    unsigned short* __restrict__ ws)
{
  const int gid = blockIdx.x * 256 + threadIdx.x;
  const int gsz = gridDim.x * 256;
  // 4 hypernet stacks: [64n][32k] winT + [2][64n][64k] wresT
  for (int i = gid; i < 4 * 10240; i += gsz) {
    int s = i / 10240, idx = i - s * 10240;
    const float* win  = (s == 0) ? hen_win  : (s == 1) ? hal_win  : (s == 2) ? how_win  : hob_win;
    const float* wres = (s == 0) ? hen_wres : (s == 1) ? hal_wres : (s == 2) ? how_wres : hob_wres;
    float v;
    if (idx < 2048) { int n = idx >> 5, k = idx & 31; v = (k < 10) ? win[k*64 + n] : 0.f; }
    else { int r = idx - 2048; int d = r >> 12; int r2 = r & 4095; int n = r2 >> 6, k = r2 & 63;
           v = wres[d*4096 + k*64 + n]; }
    ws[s * 10240 + idx] = f2b(v);
  }
  // Bg: [c][n][kl], kfg = c*32+kl: <640 -> wout'[k*10+f]; 640-649 -> bout row f; else 0
  for (int i = gid; i < 2 * 43008; i += gsz) {
    int s = i / 43008, idx = i - s * 43008;
    const float* wout = s ? hal_wout : hen_wout;
    const float* bout = s ? hal_bout : hen_bout;
    int kl = idx & 31, n = (idx >> 5) & 63, c = idx >> 11;
    int kfg = c * 32 + kl;
    float v = 0.f;
    if (kfg < 640)      { int k = kfg / 10, f = kfg - k * 10; v = wout[k*640 + f*64 + n]; }
    else if (kfg < 650) { v = bout[(kfg - 640)*64 + n]; }
    ws[(s ? OFF_BGAL : OFF_BGEN) + idx] = f2b(v);
  }
  // wiT/whT [192][64]
  for (int i = gid; i < 2 * 12288; i += gsz) {
    int s = i / 12288, idx = i - s * 12288;
    int n = idx >> 6, k = idx & 63;
    const float* w = s ? gru_wh : gru_wi;
    ws[(s ? OFF_WHT : OFF_WIT) + idx] = f2b(w[k*192 + n]);
  }
  for (int i = gid; i < 2048; i += gsz) { int n = i >> 5, k = i & 31; ws[OFF_FC1T + i] = f2b(fc1_w[k*64 + n]); }
  for (int i = gid; i < 1024; i += gsz) {
    int n = i >> 6, k = i & 63;
    float v = 0.f; if (n < 6) v = fc2_w[k*6 + n]; else if (n == 6) v = how_bout[k];
    ws[OFF_FC2E + i] = f2b(v);
  }
  for (int i = gid; i < 4096; i += gsz) ws[OFF_HOWT + i] = f2b(how_wout[i]);
  for (int i = gid; i < 1024; i += gsz) { int n = i >> 6, k = i & 63; ws[OFF_HOBT + i] = f2b(n == 0 ? hob_wout[k] : 0.f); }
}

// ================= hypernet stack: x_lds[MT][32] -> h_lds[MT][HSTR], weights direct from global
DI void run_stack(const unsigned short* x_lds, unsigned short* h_lds,
                  const unsigned short* wg, const float* bin, const float* bres,
                  int NMF, float (&hval)[3][4][4])
{
  const int t = threadIdx.x;
  const int l = t & 63, wv = t >> 6;
  const int lrow = l & 15, lk8 = (l >> 4) * 8, lr4 = (l >> 4) * 4;

  s16x8 bw[4];
  float bb0[4];
#pragma unroll
  for (int nt = 0; nt < 4; nt++) { bw[nt] = ldg8(wg + (nt*16 + lrow)*32 + lk8); bb0[nt] = bin[nt*16 + lrow]; }
#pragma unroll
  for (int i = 0; i < 3; i++) {
    int mf = wv + i * 4;
    if (mf < NMF) {
      s16x8 a = *(const s16x8*)&x_lds[(mf*16 + lrow)*32 + lk8];
#pragma unroll
      for (int nt = 0; nt < 4; nt++) {
        f32x4 d = MFMA(a, bw[nt], f32x4{0.f,0.f,0.f,0.f});
#pragma unroll
        for (int r = 0; r < 4; r++) hval[i][nt][r] = fmaxf(d[r] + bb0[nt], 0.f);
      }
#pragma unroll
      for (int nt = 0; nt < 4; nt++)
#pragma unroll
        for (int r = 0; r < 4; r++)
          h_lds[(mf*16 + lr4 + r)*HSTR + nt*16 + lrow] = f2b(hval[i][nt][r]);
    }
  }
  __syncthreads();
#pragma unroll
  for (int d = 0; d < 2; d++) {
    const unsigned short* wt = wg + 2048 + d * 4096;
    s16x8 bwr[4][2];
    float bbr[4];
#pragma unroll
    for (int nt = 0; nt < 4; nt++) {
      bbr[nt] = bres[d*64 + nt*16 + lrow];
#pragma unroll
      for (int s = 0; s < 2; s++) bwr[nt][s] = ldg8(wt + (nt*16 + lrow)*64 + s*32 + lk8);
    }
    s16x8 af[3][2];
#pragma unroll
    for (int i = 0; i < 3; i++) {
      int mf = wv + i * 4;
      if (mf < NMF) {
#pragma unroll
        for (int s = 0; s < 2; s++) af[i][s] = *(const s16x8*)&h_lds[(mf*16 + lrow)*HSTR + s*32 + lk8];
      }
    }
    __syncthreads();
#pragma unroll
    for (int i = 0; i < 3; i++) {
      int mf = wv + i * 4;
      if (mf < NMF) {
#pragma unroll
        for (int nt = 0; nt < 4; nt++) {
          f32x4 acc = {0.f,0.f,0.f,0.f};
          acc = MFMA(af[i][0], bwr[nt][0], acc);
          acc = MFMA(af[i][1], bwr[nt][1], acc);
#pragma unroll
          for (int r = 0; r < 4; r++) hval[i][nt][r] = fmaxf(acc[r] + bbr[nt], 0.f) + hval[i][nt][r];
        }
#pragma unroll
        for (int nt = 0; nt < 4; nt++)
#pragma unroll
          for (int r = 0; r < 4; r++)
            h_lds[(mf*16 + lr4 + r)*HSTR + nt*16 + lrow] = f2b(hval[i][nt][r]);
      }
    }
    __syncthreads();
  }
}

// ================= khyp_ea: stack + P-build (LDS) + wave-private K-split GEMM -> emb
__global__ __launch_bounds__(256) void khyp_ea(
    const float* __restrict__ en_feats, const float* __restrict__ al_feats,
    const unsigned short* __restrict__ ws,
    const float* __restrict__ en_bin, const float* __restrict__ en_bres,
    const float* __restrict__ al_bin, const float* __restrict__ al_bres,
    float* __restrict__ emb_en, float* __restrict__ emb_al)
{
  __shared__ __align__(16) char smem[38144];
  unsigned short* x_lds = (unsigned short*)smem;             // [MT][32]  (<= 176 rows)
  unsigned short* h_lds = (unsigned short*)(smem + 11264);   // [176][HSTR]
  unsigned short* P     = (unsigned short*)smem;             // [16][PSTR] (after stack; overlaps dead x/h)
  float* red            = (float*)(smem + PSTR*2*16);        // [4][16][64] f32 @ 21760

  const int t = threadIdx.x;
  const int l = t & 63, wv = t >> 6;
  const int lrow = l & 15, lk8 = (l >> 4) * 8, lr4 = (l >> 4) * 4;

  const bool en = blockIdx.x < 640;
  const int blk = en ? blockIdx.x : blockIdx.x - 640;
  const int E = en ? 11 : 9;
  const int MT = E * 16;
  const float* feats = (en ? en_feats : al_feats) + blk * MT * 10;
  const unsigned short* Wg = ws + (en ? OFF_WEN : OFF_WAL);
  const unsigned short* Bg = ws + (en ? OFF_BGEN : OFF_BGAL);
  const float* bin  = en ? en_bin  : al_bin;
  const float* bres = en ? en_bres : al_bres;
  float* emb = (en ? emb_en : emb_al) + blk * 1024;

  for (int idx = t; idx < MT * 32; idx += 256) {
    int row = idx >> 5, c = idx & 31;
    x_lds[idx] = (c < 10) ? f2b(feats[row*10 + c]) : (unsigned short)0;
  }
  __syncthreads();

  float hval[3][4][4];
  run_stack(x_lds, h_lds, Wg, bin, bres, E, hval);

  // ---- P-build: thread -> (agent a, k-group kg of 4)
  const int a = t >> 4, kg = t & 15, k0 = kg * 4;
  float pacc[4][10];
#pragma unroll
  for (int kk = 0; kk < 4; kk++)
#pragma unroll
    for (int f = 0; f < 10; f++) pacc[kk][f] = 0.f;
  float sx[10];
#pragma unroll
  for (int f = 0; f < 10; f++) sx[f] = 0.f;
  for (int e = 0; e < E; e++) {
    int row = a * E + e;
    s16x4 hv4 = *(const s16x4*)&h_lds[row*HSTR + k0];
    s16x8 xv8 = *(const s16x8*)&x_lds[row*32];
    unsigned xv2 = *(const unsigned*)&x_lds[row*32 + 8];
    float xf[10];
#pragma unroll
    for (int f = 0; f < 8; f++) xf[f] = b2f((unsigned short)xv8[f]);
    xf[8] = b2f((unsigned short)(xv2 & 0xFFFF));
    xf[9] = b2f((unsigned short)(xv2 >> 16));
    float hf[4];
#pragma unroll
    for (int kk = 0; kk < 4; kk++) hf[kk] = b2f((unsigned short)hv4[kk]);
#pragma unroll
    for (int kk = 0; kk < 4; kk++)
#pragma unroll
      for (int f = 0; f < 10; f++) pacc[kk][f] += hf[kk] * xf[f];
    if (kg == 0) {
#pragma unroll
      for (int f = 0; f < 10; f++) sx[f] += xf[f];
    }
  }
  __syncthreads();   // all x/h reads done before P overwrites that LDS
#pragma unroll
  for (int kk = 0; kk < 4; kk++)
#pragma unroll
    for (int f = 0; f < 10; f++)
      P[a*PSTR + (k0 + kk)*10 + f] = f2b(pacc[kk][f]);
  if (kg == 0) {
#pragma unroll
    for (int f = 0; f < 10; f++) P[a*PSTR + 640 + f] = f2b(sx[f]);
  }
  for (int i = t; i < 352; i += 256) { int a2 = i / 22, c = i - (i/22)*22; P[a2*PSTR + 650 + c] = 0; }
  __syncthreads();   // P ready

  // ---- GEMM: wave wv owns chunks c = wv, wv+4, ... (barrier-free), B direct from global
  f32x4 gacc[4];
#pragma unroll
  for (int nt = 0; nt < 4; nt++) gacc[nt] = f32x4{0.f,0.f,0.f,0.f};
  int c = wv;
  s16x8 afr = *(const s16x8*)&P[lrow*PSTR + c*32 + lk8];
  s16x8 bfr[4];
#pragma unroll
  for (int nt = 0; nt < 4; nt++) bfr[nt] = ldg8(Bg + (c*64 + nt*16 + lrow)*32 + lk8);
  while (c < 21) {
    int cn = c + 4;
    s16x8 afn = afr;
    s16x8 bfn[4] = {bfr[0], bfr[1], bfr[2], bfr[3]};
    if (cn < 21) {
      afn = *(const s16x8*)&P[lrow*PSTR + cn*32 + lk8];
#pragma unroll
      for (int nt = 0; nt < 4; nt++) bfn[nt] = ldg8(Bg + (cn*64 + nt*16 + lrow)*32 + lk8);
    }
#pragma unroll
    for (int nt = 0; nt < 4; nt++) gacc[nt] = MFMA(afr, bfr[nt], gacc[nt]);
    afr = afn;
#pragma unroll
    for (int nt = 0; nt < 4; nt++) bfr[nt] = bfn[nt];
    c = cn;
  }
#pragma unroll
  for (int nt = 0; nt < 4; nt++)
#pragma unroll
    for (int r = 0; r < 4; r++)
      red[(wv*16 + lr4 + r)*64 + nt*16 + lrow] = gacc[nt][r];
  __syncthreads();
#pragma unroll
  for (int rep = 0; rep < 4; rep++) {
    int idx = t + rep * 256;
    int aa = idx >> 6, j = idx & 63;
    emb[aa*64 + j] = red[aa*64 + j] + red[(16+aa)*64 + j] + red[(32+aa)*64 + j] + red[(48+aa)*64 + j];
  }
}

// ================= kfused: fc1 + embeds + GRU + fc2/hb + g  (all MFMA)
__global__ __launch_bounds__(256) void kfused(
    const float* __restrict__ own, const float* __restrict__ agent_emb,
    const float* __restrict__ action_emb,
    const int* __restrict__ agent_idx, const int* __restrict__ last_action,
    const float* __restrict__ emb_en, const float* __restrict__ emb_al,
    const float* __restrict__ hidden,
    const unsigned short* __restrict__ ws,
    const float* __restrict__ fc1_b, const float* __restrict__ bi,
    const float* __restrict__ bh, const float* __restrict__ fc2_b,
    float* __restrict__ qout, float* __restrict__ hhout,
    unsigned short* __restrict__ g_bf, float* __restrict__ hb)
{
  __shared__ unsigned short own_lds[16*32];
  __shared__ unsigned short x_lds[16*HSTR];
  __shared__ unsigned short hp_lds[16*HSTR];
  __shared__ unsigned short hh_lds[16*HSTR];
  const int t = threadIdx.x;
  const int l = t & 63, wv = t >> 6;
  const int lrow = l & 15, lk8 = (l >> 4) * 8, lr4 = (l >> 4) * 4;
  const int n0 = blockIdx.x * 16;

  const unsigned short* fc1T = ws + OFF_FC1T;
  const unsigned short* wiT  = ws + OFF_WIT;
  const unsigned short* whT  = ws + OFF_WHT;
  const unsigned short* howT = ws + OFF_HOWT;
  const unsigned short* fc2e = ws + OFF_FC2E;

  for (int i = t; i < 512; i += 256) own_lds[i] = f2b(own[n0*32 + i]);
  for (int i = t; i < 1024; i += 256) hp_lds[(i >> 6)*HSTR + (i & 63)] = f2b(hidden[n0*64 + i]);
  __syncthreads();

  const int j = wv * 16 + lrow;
  {  // fc1 + gathers -> x
    s16x8 a0 = *(const s16x8*)&own_lds[lrow*32 + lk8];
    s16x8 b0 = ldg8(fc1T + (wv*16 + lrow)*32 + lk8);
    f32x4 c0 = MFMA(a0, b0, f32x4{0.f,0.f,0.f,0.f});
    float fb = fc1_b[j];
#pragma unroll
    for (int r = 0; r < 4; r++) {
      int aa = lr4 + r; int n = n0 + aa;
      int ai = agent_idx[n], la = last_action[n];
      float v = c0[r] + fb + agent_emb[ai*64 + j] + action_emb[la*64 + j]
              + emb_en[n*64 + j] + emb_al[n*64 + j];
      x_lds[aa*HSTR + j] = f2b(fmaxf(v, 0.f));
    }
  }
  __syncthreads();

  {  // GRU
    s16x8 xa[2], ha[2];
#pragma unroll
    for (int s = 0; s < 2; s++) {
      xa[s] = *(const s16x8*)&x_lds[lrow*HSTR + s*32 + lk8];
      ha[s] = *(const s16x8*)&hp_lds[lrow*HSTR + s*32 + lk8];
    }
    f32x4 gi[3], gh[3];
#pragma unroll
    for (int g3 = 0; g3 < 3; g3++) { gi[g3] = f32x4{0.f,0.f,0.f,0.f}; gh[g3] = f32x4{0.f,0.f,0.f,0.f}; }
#pragma unroll
    for (int g3 = 0; g3 < 3; g3++) {
      int tl = wv + g3 * 4;
#pragma unroll
      for (int s = 0; s < 2; s++) {
        gi[g3] = MFMA(xa[s], ldg8(wiT + (tl*16 + lrow)*64 + s*32 + lk8), gi[g3]);
        gh[g3] = MFMA(ha[s], ldg8(whT + (tl*16 + lrow)*64 + s*32 + lk8), gh[g3]);
      }
    }
    float bir = bi[j], biz = bi[64 + j], bin_ = bi[128 + j];
    float bhr = bh[j], bhz = bh[64 + j], bhn = bh[128 + j];
#pragma unroll
    for (int r = 0; r < 4; r++) {
      int aa = lr4 + r; int n = n0 + aa;
      float rr = 1.f / (1.f + __expf(-(gi[0][r] + bir + gh[0][r] + bhr)));
      float zz = 1.f / (1.f + __expf(-(gi[1][r] + biz + gh[1][r] + bhz)));
      float nn = tanhf(gi[2][r] + bin_ + rr * (gh[2][r] + bhn));
      float hp = hidden[n*64 + j];
      float hhv = (1.f - zz) * nn + zz * hp;
      hhout[n*64 + j] = hhv;
      hh_lds[aa*HSTR + j] = f2b(hhv);
    }
  }
  __syncthreads();

  {  // g = hh @ howT ; fc2ext (q_normal + hb)
    s16x8 hha[2];
#pragma unroll
    for (int s = 0; s < 2; s++) hha[s] = *(const s16x8*)&hh_lds[lrow*HSTR + s*32 + lk8];
    f32x4 gc = {0.f,0.f,0.f,0.f};
#pragma unroll
    for (int s = 0; s < 2; s++) gc = MFMA(hha[s], ldg8(howT + (wv*16 + lrow)*64 + s*32 + lk8), gc);
#pragma unroll
    for (int r = 0; r < 4; r++) g_bf[(n0 + lr4 + r)*64 + wv*16 + lrow] = f2b(gc[r]);
    if (wv == 0) {
      f32x4 qc = {0.f,0.f,0.f,0.f};
#pragma unroll
      for (int s = 0; s < 2; s++) qc = MFMA(hha[s], ldg8(fc2e + lrow*64 + s*32 + lk8), qc);
#pragma unroll
      for (int r = 0; r < 4; r++) {
        int n = n0 + lr4 + r;
        if (lrow < 6)       qout[n*17 + lrow] = qc[r] + fc2_b[lrow];
        else if (lrow == 6) hb[n] = qc[r];
      }
    }
  }
}

// ================= kattack: hob stack -> qB; how stack -> q_attack
__global__ __launch_bounds__(256) void kattack(
    const float* __restrict__ en_feats, const unsigned short* __restrict__ ws,
    const float* __restrict__ how_bin, const float* __restrict__ how_bres,
    const float* __restrict__ hob_bin, const float* __restrict__ hob_bres,
    const unsigned short* __restrict__ g_bf, const float* __restrict__ hb,
    const float* __restrict__ hob_bout, float* __restrict__ qout)
{
  __shared__ __align__(16) unsigned short x_lds[176*32];
  __shared__ __align__(16) unsigned short h_lds[176*HSTR];
  __shared__ float qB[176];
  const int t = threadIdx.x;
  const int l = t & 63, wv = t >> 6;
  const int lrow = l & 15, lk8 = (l >> 4) * 8, lr4 = (l >> 4) * 4;
  const int blk = blockIdx.x;
  const float* feats = en_feats + blk * 1760;

  for (int idx = t; idx < 176*32; idx += 256) {
    int row = idx >> 5, c = idx & 31;
    x_lds[idx] = (c < 10) ? f2b(feats[row*10 + c]) : (unsigned short)0;
  }
  __syncthreads();

  float hval[3][4][4];
  run_stack(x_lds, h_lds, ws + OFF_WHOB, hob_bin, hob_bres, 11, hval);

#pragma unroll
  for (int i = 0; i < 3; i++) {   // qB = h_hob . hob_wout  (col 0 of hobT tile)
    int mf = wv + i * 4;
    if (mf < 11) {
      s16x8 aa0 = *(const s16x8*)&h_lds[(mf*16 + lrow)*HSTR + lk8];
      s16x8 aa1 = *(const s16x8*)&h_lds[(mf*16 + lrow)*HSTR + 32 + lk8];
      f32x4 qc = {0.f,0.f,0.f,0.f};
      qc = MFMA(aa0, ldg8(ws + OFF_HOBT + lrow*64 + lk8), qc);
      qc = MFMA(aa1, ldg8(ws + OFF_HOBT + lrow*64 + 32 + lk8), qc);
      if (lrow == 0) {
#pragma unroll
        for (int r = 0; r < 4; r++) qB[mf*16 + lr4 + r] = qc[r];
      }
    }
  }
  __syncthreads();

  run_stack(x_lds, h_lds, ws + OFF_WHOW, how_bin, how_bres, 11, hval);

  float hob_b0 = hob_bout[0];
#pragma unroll
  for (int i = 0; i < 3; i++) {   // C[row][agent] = h_how . g[agent]; keep agent == row/11
    int mf = wv + i * 4;
    if (mf < 11) {
      s16x8 aa0 = *(const s16x8*)&h_lds[(mf*16 + lrow)*HSTR + lk8];
      s16x8 aa1 = *(const s16x8*)&h_lds[(mf*16 + lrow)*HSTR + 32 + lk8];
      f32x4 qc = {0.f,0.f,0.f,0.f};
      qc = MFMA(aa0, ldg8(g_bf + (blk*16 + lrow)*64 + lk8), qc);
      qc = MFMA(aa1, ldg8(g_bf + (blk*16 + lrow)*64 + 32 + lk8), qc);
#pragma unroll
      for (int r = 0; r < 4; r++) {
        int row = mf*16 + lr4 + r;
        int ag = row / 11;
        if (ag == lrow) {
          int e = row - ag * 11;
          int n = blk*16 + ag;
          qout[n*17 + 6 + e] = qc[r] + qB[row] + hb[n] + hob_b0;
        }
      }
    }
  }
}

extern "C" void kernel_launch(void* const* d_in, const int* in_sizes, int n_in,
                              void* d_out, int out_size, void* d_ws, size_t ws_size,
                              hipStream_t stream)
{
  (void)in_sizes; (void)n_in; (void)out_size; (void)ws_size;
  const float* own        = (const float*)d_in[0];
  const float* enemy      = (const float*)d_in[1];
  const float* ally       = (const float*)d_in[2];
  const float* hidden     = (const float*)d_in[3];
  const float* fc1_w      = (const float*)d_in[4];
  const float* fc1_b      = (const float*)d_in[5];
  const float* agent_emb  = (const float*)d_in[6];
  const float* action_emb = (const float*)d_in[7];
  const float* hen_win  = (const float*)d_in[8];  const float* hen_bin  = (const float*)d_in[9];
  const float* hen_wres = (const float*)d_in[10]; const float* hen_bres = (const float*)d_in[11];
  const float* hen_wout = (const float*)d_in[12]; const float* hen_bout = (const float*)d_in[13];
  const float* hal_win  = (const float*)d_in[14]; const float* hal_bin  = (const float*)d_in[15];
  const float* hal_wres = (const float*)d_in[16]; const float* hal_bres = (const float*)d_in[17];
  const float* hal_wout = (const float*)d_in[18]; const float* hal_bout = (const float*)d_in[19];
  const float* gru_wi = (const float*)d_in[20];   const float* gru_wh = (const float*)d_in[21];
  const float* gru_bi = (const float*)d_in[22];   const float* gru_bh = (const float*)d_in[23];
  const float* fc2_w  = (const float*)d_in[24];   const float* fc2_b  = (const float*)d_in[25];
  const float* how_win  = (const float*)d_in[26]; const float* how_bin  = (const float*)d_in[27];
  const float* how_wres = (const float*)d_in[28]; const float* how_bres = (const float*)d_in[29];
  const float* how_wout = (const float*)d_in[30]; const float* how_bout = (const float*)d_in[31];
  const float* hob_win  = (const float*)d_in[32]; const float* hob_bin  = (const float*)d_in[33];
  const float* hob_wres = (const float*)d_in[34]; const float* hob_bres = (const float*)d_in[35];
  const float* hob_wout = (const float*)d_in[36]; const float* hob_bout = (const float*)d_in[37];
  const int* agent_idx   = (const int*)d_in[38];
  const int* last_action = (const int*)d_in[39];

  unsigned short* ws = (unsigned short*)d_ws;
  float* emb_en = (float*)((char*)d_ws + B_EMB_EN);
  float* emb_al = (float*)((char*)d_ws + B_EMB_AL);
  float* hb     = (float*)((char*)d_ws + B_HB);
  unsigned short* g_bf = (unsigned short*)((char*)d_ws + B_GBF);

  float* q  = (float*)d_out;
  float* hh = q + 1024*10*17;

  kprep<<<128, 256, 0, stream>>>(hen_win, hen_wres, hal_win, hal_wres,
      how_win, how_wres, hob_win, hob_wres,
      hen_wout, hen_bout, hal_wout, hal_bout,
      gru_wi, gru_wh, fc1_w, fc2_w, how_bout, how_wout, hob_wout, ws);
  khyp_ea<<<1280, 256, 0, stream>>>(enemy, ally, ws,
      hen_bin, hen_bres, hal_bin, hal_bres, emb_en, emb_al);
  kfused<<<640, 256, 0, stream>>>(own, agent_emb, action_emb, agent_idx, last_action,
      emb_en, emb_al, hidden, ws, fc1_b, gru_bi, gru_bh, fc2_b, q, hh, g_bf, hb);
  kattack<<<640, 256, 0, stream>>>(enemy, ws, how_bin, how_bres, hob_bin, hob_bres,
      g_bf, hb, hob_bout, q);
}